// Round 5
// baseline (266.690 us; speedup 1.0000x reference)
//
#include <hip/hip_runtime.h>
#include <hip/hip_bf16.h>

#define B_  4
#define S_  2048
#define E_  1024
#define H_  16
#define DH_ 64
#define M_  (B_*S_)    // 8192 rows
#define HD_ (H_*DH_)   // 1024

typedef unsigned short u16;
typedef __attribute__((ext_vector_type(8))) __bf16 bf16x8;
typedef __attribute__((ext_vector_type(4))) __bf16 bf16x4;
typedef __attribute__((ext_vector_type(4))) float  f32x4;

#if __has_builtin(__builtin_amdgcn_exp2f)
#define EXP2F __builtin_amdgcn_exp2f
#else
#define EXP2F __builtin_exp2f
#endif

// softmax scale folded into Q at QKV epilogue: 1/sqrt(64) * log2(e)
#define QSCALE 0.18033688011112042f

// ---- async global->LDS, 16B per lane ----
__device__ __forceinline__ void g2l16(const void* g, void* l) {
  __builtin_amdgcn_global_load_lds(
      (const __attribute__((address_space(1))) void*)g,
      (__attribute__((address_space(3))) void*)l, 16, 0, 0);
}

// RNE float -> bf16 bits (scalar path, used in prep only)
__device__ __forceinline__ u16 f2bf(float f) {
  union { float f; unsigned u; } v; v.f = f;
  unsigned r = v.u + 0x7FFFu + ((v.u >> 16) & 1u);
  return (u16)(r >> 16);
}

// ---------------- fused prep: cvt_x | pack_wqkv | pack_wo ----------------
__global__ __launch_bounds__(256) void prep_kernel(
    const float* __restrict__ x, const float* __restrict__ Wq,
    const float* __restrict__ Wk, const float* __restrict__ Wv,
    const float* __restrict__ Wo,
    u16* __restrict__ xb, u16* __restrict__ wqkvT, u16* __restrict__ woT) {
  __shared__ u16 tile[64][66];
  const int blk = blockIdx.x, tid = threadIdx.x;
  if (blk < 8192) {
    int i = blk * 256 + tid;
    float4 v = ((const float4*)x)[i];
    ushort4 o;
    o.x = f2bf(v.x); o.y = f2bf(v.y); o.z = f2bf(v.z); o.w = f2bf(v.w);
    ((ushort4*)xb)[i] = o;
  } else if (blk < 8960) {
    int b2 = blk - 8192;
    int p = b2 >> 8, h = (b2 >> 4) & 15, e0 = (b2 & 15) * 64;
    const float* src = (p == 0 ? Wq : (p == 1 ? Wk : Wv)) + h * (E_ * DH_);
#pragma unroll
    for (int r = 0; r < 16; ++r) {
      int idx = r * 256 + tid;
      int el = idx >> 6, d = idx & 63;
      tile[el][d] = f2bf(src[(e0 + el) * DH_ + d]);
    }
    __syncthreads();
    u16* dst = wqkvT + (p * HD_ + h * DH_) * E_;
#pragma unroll
    for (int r = 0; r < 16; ++r) {
      int idx = r * 256 + tid;
      int d = idx >> 6, el = idx & 63;
      dst[d * E_ + e0 + el] = tile[el][d];
    }
  } else {
    int b3 = blk - 8960;
    int c0 = (b3 >> 4) * 64, e0 = (b3 & 15) * 64;
#pragma unroll
    for (int r = 0; r < 16; ++r) {
      int idx = r * 256 + tid;
      int cl = idx >> 6, el = idx & 63;
      tile[cl][el] = f2bf(Wo[(c0 + cl) * E_ + e0 + el]);
    }
    __syncthreads();
#pragma unroll
    for (int r = 0; r < 16; ++r) {
      int idx = r * 256 + tid;
      int er = idx >> 6, cl = idx & 63;
      woT[(e0 + er) * HD_ + c0 + cl] = tile[cl][er];
    }
  }
}

// ---------------- GEMM: C[M][N] = A[M][K] * Bt[N][K]^T, K = 1024, BK = 64 ----
// MODE 0: QKV epilogue — bias, bf16, then LDS round-trip to emit 16B coalesced
//         stores. Q/K in [m][cc] orientation; V written DIRECTLY as V^T
//         [b,h,d,s] via [cc][m] orientation (no separate transpose kernel).
// MODE 1: out-proj epilogue (b0=bo; bias + fp32 direct store)
// R3 NOTE: a 128x256 2-phase/setprio/counted-vmcnt variant (1 block/CU) was
// measured == this kernel (265.2 vs 261.5 total); partial 8-phase grafts
// don't pay without the full template. Keep this 3-blocks/CU structure.
template <int MODE>
__global__ __launch_bounds__(256) void gemm_bt_kernel(
    const u16* __restrict__ A, const u16* __restrict__ Bt,
    const float* __restrict__ b0, const float* __restrict__ b1,
    const float* __restrict__ b2,
    u16* __restrict__ oQ, u16* __restrict__ oK, u16* __restrict__ oV,
    float* __restrict__ oF) {
  constexpr int K = 1024;
  __shared__ __align__(16) u16 smem[2 * 128 * 64];   // As | Bs; reused as C-tile
  u16* As = smem;
  u16* Bs = smem + 128 * 64;
  const int tid = threadIdx.x;
  const int lane = tid & 63, wv = tid >> 6;
  const int wm = (wv >> 1) * 64, wn = (wv & 1) * 64;
  const int q4 = lane >> 4, lm = lane & 15;
  const int tileM = blockIdx.y * 128, tileN = blockIdx.x * 128;

  const u16* gA[4]; const u16* gB[4]; u16* lA[4]; u16* lB[4];
#pragma unroll
  for (int rr = 0; rr < 4; ++rr) {
    int c = rr * 256 + tid;
    int r = c >> 3, sw = ((c & 7) ^ (r & 7)) * 8;
    gA[rr] = A + (size_t)(tileM + r) * K + sw;
    gB[rr] = Bt + (size_t)(tileN + r) * K + sw;
    lA[rr] = As + c * 8;
    lB[rr] = Bs + c * 8;
  }

  f32x4 acc[4][4] = {};

  int aoff[2][4], boff[2][4];
#pragma unroll
  for (int ks = 0; ks < 2; ++ks) {
#pragma unroll
    for (int i = 0; i < 4; ++i) {
      int ra = wm + i * 16 + lm;
      aoff[ks][i] = ra * 64 + (((ks * 4 + q4) ^ (ra & 7)) * 8);
      int rb = wn + i * 16 + lm;
      boff[ks][i] = rb * 64 + (((ks * 4 + q4) ^ (rb & 7)) * 8);
    }
  }

  for (int k0 = 0; k0 < K; k0 += 64) {
#pragma unroll
    for (int rr = 0; rr < 4; ++rr) {
      g2l16(gA[rr] + k0, lA[rr]);
      g2l16(gB[rr] + k0, lB[rr]);
    }
    __syncthreads();
#pragma unroll
    for (int ks = 0; ks < 2; ++ks) {
      bf16x8 af[4], bf[4];
#pragma unroll
      for (int i = 0; i < 4; ++i) af[i] = *(const bf16x8*)(As + aoff[ks][i]);
#pragma unroll
      for (int j = 0; j < 4; ++j) bf[j] = *(const bf16x8*)(Bs + boff[ks][j]);
#pragma unroll
      for (int i = 0; i < 4; ++i)
#pragma unroll
        for (int j = 0; j < 4; ++j)
          acc[i][j] = __builtin_amdgcn_mfma_f32_16x16x32_bf16(af[i], bf[j], acc[i][j], 0, 0, 0);
    }
    __syncthreads();
  }

  if (MODE == 1) {
#pragma unroll
    for (int j = 0; j < 4; ++j) {
      int n = tileN + wn + j * 16 + lm;
      float bs = b0[n];
#pragma unroll
      for (int i = 0; i < 4; ++i) {
        int m0 = tileM + wm + i * 16 + q4 * 4;
#pragma unroll
        for (int r = 0; r < 4; ++r) oF[(m0 + r) * HD_ + n] = acc[i][j][r] + bs;
      }
    }
  } else {
    // ---- LDS round-trip epilogue (after final barrier, smem is free) ----
    u16* TT = smem;                        // 128 x 128 bf16, swizzled
    const int ccb = tileN & 1023;
    const int proj = tileN >> 10;          // uniform per block
    const float scl = (proj == 0 ? QSCALE : 1.0f);
    const float* bp = (proj == 0 ? b0 : (proj == 1 ? b1 : b2));
#pragma unroll
    for (int j = 0; j < 4; ++j) {
      int ncl = wn + j * 16 + lm;
      float bs = bp[ccb + ncl];
#pragma unroll
      for (int i = 0; i < 4; ++i) {
        int m0 = wm + i * 16 + q4 * 4;
        f32x4 vv;
#pragma unroll
        for (int r = 0; r < 4; ++r) vv[r] = (acc[i][j][r] + bs) * scl;
        bf16x4 ov = __builtin_convertvector(vv, bf16x4);
        if (proj < 2) {
          // orientation A: element (ml, ccl) at ml*128 + (ccl ^ 8*(ml&15))
          ushort4 us = *(ushort4*)&ov;
          TT[(m0 + 0) * 128 + (ncl ^ (8 * ((m0 + 0) & 15)))] = us.x;
          TT[(m0 + 1) * 128 + (ncl ^ (8 * ((m0 + 1) & 15)))] = us.y;
          TT[(m0 + 2) * 128 + (ncl ^ (8 * ((m0 + 2) & 15)))] = us.z;
          TT[(m0 + 3) * 128 + (ncl ^ (8 * ((m0 + 3) & 15)))] = us.w;
        } else {
          // orientation B: element (ccl, ml) at ccl*128 + (ml ^ 8*(ccl&15))
          *(bf16x4*)(TT + ncl * 128 + (m0 ^ (8 * (ncl & 15)))) = ov;  // b64
        }
      }
    }
    __syncthreads();
    if (proj < 2) {
      u16* optr = (proj == 0 ? oQ : oK);
#pragma unroll
      for (int rr = 0; rr < 8; ++rr) {
        int seg = rr * 256 + tid;
        int ml = seg >> 4, sc = (seg & 15) * 8;
        uint4 val = *(const uint4*)(TT + ml * 128 + (sc ^ (8 * (ml & 15))));
        *(uint4*)(optr + (size_t)(tileM + ml) * 1024 + ccb + sc) = val;
      }
    } else {
      const int bb = tileM >> 11, s0 = tileM & 2047;
#pragma unroll
      for (int rr = 0; rr < 8; ++rr) {
        int seg = rr * 256 + tid;
        int ccl = seg >> 4, sc = (seg & 15) * 8;
        int cc = ccb + ccl;
        int hh = cc >> 6, dd = cc & 63;
        uint4 val = *(const uint4*)(TT + ccl * 128 + (sc ^ (8 * (ccl & 15))));
        *(uint4*)(oV + ((size_t)(bb * 16 + hh) * 64 + dd) * 2048 + s0 + sc) = val;
      }
    }
  }
}

// ---------------- flash attention — R5: QK pipelined one tile ahead ----------------
// R4 post-mortem: occupancy 17.8->34% bought only -3%; pipes each ~44% busy,
// time ~ SUM of MFMA+VALU+LDS, not max — in-wave chain QK->exp->pack->PV
// serializes and lockstepped waves burst one pipe at a time.
// R5 mechanism (T15): triple-buffer K; at iter t compute S(t+1)=QK(K[t+1])
// FIRST (independent -> fills MFMA pipe), then exp/pack of saved S(t) (VALU
// under MFMA shadow), then li+PV(t). All dependencies 1 tile apart.
// Two named S-states rotated by 2x-unrolled loop (no runtime reg indexing).
// Slot safety: K-slot written at t was last read at t-2 (2 barriers apart);
// V-slot written at t last read at t-1 (1 barrier + write issues post-barrier).
// LDS 40 KiB -> 4 blocks/CU (grid 1024 = 4/CU exact).
// KEY PERMUTATION unchanged (verified R0-R4): K rows staged at LDS slot
// s = kb*16+q4*4+r hold logical key kperm(s) = (kb&1)*32+q4*8+(kb>>1)*4+r.
// REGISTER RULE: keep launch_bounds (256,2); tighter -> spill storm.
__global__ __launch_bounds__(256, 2) void flash_kernel(
    const u16* __restrict__ Q, const u16* __restrict__ Kb,
    const u16* __restrict__ Vt, u16* __restrict__ Z) {
  __shared__ __align__(16) u16 Ks[3][64 * 64];   // [slot][d] swizzled, key-permuted
  __shared__ __align__(16) u16 Vs[2][64 * 64];   // [d][key] swizzled, sequential
  const int tid = threadIdx.x, lane = tid & 63, wv = tid >> 6;
  const int q4 = lane >> 4, lm = lane & 15;

  const int bid = blockIdx.x;
  const int bh = bid >> 4, qt = bid & 15;        // 16 consecutive blocks share (b,h) K/V
  const int b = bh >> 4, h = bh & 15;

  const u16* qbase = Q + ((size_t)(b * S_ + qt * 128)) * HD_ + h * DH_;
  const u16* kbase = Kb + (size_t)b * S_ * HD_ + h * DH_;
  const u16* vbase = Vt + ((size_t)(b * H_ + h)) * DH_ * S_;
  u16* zbase = Z + ((size_t)(b * S_ + qt * 128)) * HD_ + h * DH_;

  const int c0 = tid,       r0 = c0 >> 3, s0 = ((c0 & 7) ^ (r0 & 7)) * 8;
  const int c1 = tid + 256, r1 = c1 >> 3, s1 = ((c1 & 7) ^ (r1 & 7)) * 8;
  const int kr0 = ((r0 >> 4) & 1) * 32 + ((r0 >> 2) & 3) * 8 + (r0 >> 5) * 4 + (r0 & 3);
  const int kr1 = ((r1 >> 4) & 1) * 32 + ((r1 >> 2) & 3) * 8 + (r1 >> 5) * 4 + (r1 & 3);

  bf16x8 qf[2][2];
#pragma unroll
  for (int qs = 0; qs < 2; ++qs)
#pragma unroll
    for (int dc = 0; dc < 2; ++dc)
      qf[qs][dc] = *(const bf16x8*)(qbase + (wv * 32 + qs * 16 + lm) * HD_ + dc * 32 + q4 * 8);

  const bf16x8 ones = {(__bf16)1.f, (__bf16)1.f, (__bf16)1.f, (__bf16)1.f,
                       (__bf16)1.f, (__bf16)1.f, (__bf16)1.f, (__bf16)1.f};

  // fragment base offsets (d-chunk 0 / 1); kb/db contribute imm kb*1024/db*1024
  const int base0 = lm * 64 + ((q4 ^ (lm & 7)) * 8);
  const int base1 = lm * 64 + (((4 + q4) ^ (lm & 7)) * 8);

  f32x4 oacc[2][4] = {};
  f32x4 liacc[2] = {};

  auto stage_k = [&](int slot, int t) {
    const u16* kt = kbase + (size_t)t * 64 * HD_;
    g2l16(kt + kr0 * HD_ + s0, Ks[slot] + c0 * 8);
    g2l16(kt + kr1 * HD_ + s1, Ks[slot] + c1 * 8);
  };
  auto stage_v = [&](int slot, int t) {
    const u16* vt = vbase + t * 64;
    g2l16(vt + r0 * S_ + s0, Vs[slot] + c0 * 8);
    g2l16(vt + r1 * S_ + s1, Vs[slot] + c1 * 8);
  };

  // QK for one tile into state SS[ck][qs][{a,b}]
  auto qk_tile = [&](f32x4 (&SS)[2][2][2], int kslot) {
    const u16* Kp = Ks[kslot];
#pragma unroll
    for (int ck = 0; ck < 2; ++ck) {
      bf16x8 ka0 = *(const bf16x8*)(Kp + ck * 1024 + base0);
      bf16x8 ka1 = *(const bf16x8*)(Kp + ck * 1024 + base1);
      bf16x8 kb0 = *(const bf16x8*)(Kp + (ck + 2) * 1024 + base0);
      bf16x8 kb1 = *(const bf16x8*)(Kp + (ck + 2) * 1024 + base1);
#pragma unroll
      for (int qs = 0; qs < 2; ++qs) {
        f32x4 sa = {}, sb = {};
        sa = __builtin_amdgcn_mfma_f32_16x16x32_bf16(ka0, qf[qs][0], sa, 0, 0, 0);
        sa = __builtin_amdgcn_mfma_f32_16x16x32_bf16(ka1, qf[qs][1], sa, 0, 0, 0);
        sb = __builtin_amdgcn_mfma_f32_16x16x32_bf16(kb0, qf[qs][0], sb, 0, 0, 0);
        sb = __builtin_amdgcn_mfma_f32_16x16x32_bf16(kb1, qf[qs][1], sb, 0, 0, 0);
        SS[ck][qs][0] = sa; SS[ck][qs][1] = sb;
      }
    }
  };

  // exp/pack + li + PV for saved state SS against V slot
  auto smpv = [&](f32x4 (&SS)[2][2][2], int vslot) {
    const u16* Vp = Vs[vslot];
#pragma unroll
    for (int ck = 0; ck < 2; ++ck) {
      bf16x8 pf[2];
#pragma unroll
      for (int qs = 0; qs < 2; ++qs) {
        f32x4 pa, pb2;
#pragma unroll
        for (int r = 0; r < 4; ++r) {
          pa[r]  = EXP2F(SS[ck][qs][0][r]);
          pb2[r] = EXP2F(SS[ck][qs][1][r]);
        }
        bf16x4 la = __builtin_convertvector(pa, bf16x4);
        bf16x4 lb = __builtin_convertvector(pb2, bf16x4);
        pf[qs] = __builtin_shufflevector(la, lb, 0, 1, 2, 3, 4, 5, 6, 7);
      }
      const int vsel = ck ? base1 : base0;
      __builtin_amdgcn_s_setprio(1);
#pragma unroll
      for (int qs = 0; qs < 2; ++qs)
        liacc[qs] = __builtin_amdgcn_mfma_f32_16x16x32_bf16(pf[qs], ones, liacc[qs], 0, 0, 0);
#pragma unroll
      for (int db = 0; db < 4; ++db) {
        bf16x8 vf = *(const bf16x8*)(Vp + db * 1024 + vsel);
#pragma unroll
        for (int qs = 0; qs < 2; ++qs)
          oacc[qs][db] = __builtin_amdgcn_mfma_f32_16x16x32_bf16(pf[qs], vf, oacc[qs][db], 0, 0, 0);
      }
      __builtin_amdgcn_s_setprio(0);
    }
  };

  f32x4 sE[2][2][2], sO[2][2][2];

  // prologue: K0->slot0, V0->vs0, K1->slot1; drain; S(0)
  stage_k(0, 0); stage_v(0, 0); stage_k(1, 1);
  __syncthreads();
  qk_tile(sE, 0);

  auto body = [&](f32x4 (&SC)[2][2][2], f32x4 (&SN)[2][2][2], int t) {
    __syncthreads();                       // staged data from t-1 is resident
    if (t < 30) stage_k((t + 2) % 3, t + 2);
    if (t < 31) stage_v((t + 1) & 1, t + 1);
    if (t < 31) qk_tile(SN, (t + 1) % 3);  // independent MFMA burst first
    smpv(SC, t & 1);                       // VALU + PV of saved tile
  };

  for (int t = 0; t < 32; t += 2) {
    body(sE, sO, t);
    body(sO, sE, t + 1);
  }

  // ---- normalize + store (wave owns its 32 q-rows; li is in-lane) ----
#pragma unroll
  for (int qs = 0; qs < 2; ++qs) {
    float rin[4];
#pragma unroll
    for (int r = 0; r < 4; ++r) rin[r] = 1.f / liacc[qs][r];
#pragma unroll
    for (int db = 0; db < 4; ++db) {
      f32x4 vv;
#pragma unroll
      for (int r = 0; r < 4; ++r) vv[r] = oacc[qs][db][r] * rin[r];
      bf16x4 ov = __builtin_convertvector(vv, bf16x4);
      ushort4 us = *(ushort4*)&ov;
      int m0 = wv * 32 + qs * 16 + q4 * 4;
      zbase[(m0 + 0) * HD_ + db * 16 + lm] = us.x;
      zbase[(m0 + 1) * HD_ + db * 16 + lm] = us.y;
      zbase[(m0 + 2) * HD_ + db * 16 + lm] = us.z;
      zbase[(m0 + 3) * HD_ + db * 16 + lm] = us.w;
    }
  }
}

// ---------------- host ----------------
extern "C" void kernel_launch(void* const* d_in, const int* in_sizes, int n_in,
                              void* d_out, int out_size, void* d_ws, size_t ws_size,
                              hipStream_t stream) {
  const float* x  = (const float*)d_in[0];
  const float* Wq = (const float*)d_in[1];
  const float* bq = (const float*)d_in[2];
  const float* Wk = (const float*)d_in[3];
  const float* bk = (const float*)d_in[4];
  const float* Wv = (const float*)d_in[5];
  const float* bv = (const float*)d_in[6];
  const float* Wo = (const float*)d_in[7];
  const float* bo = (const float*)d_in[8];
  float* out = (float*)d_out;

  char* w = (char*)d_ws;
  u16*   xb    = (u16*)w;   w += (size_t)M_ * E_ * 2;
  u16*   wqkvT = (u16*)w;   w += (size_t)3 * HD_ * E_ * 2;
  u16*   woT   = (u16*)w;   w += (size_t)E_ * HD_ * 2;
  u16*   qB    = (u16*)w;   w += (size_t)M_ * HD_ * 2;
  u16*   kB    = (u16*)w;   w += (size_t)M_ * HD_ * 2;
  u16*   vT    = (u16*)w;   w += (size_t)M_ * HD_ * 2;     // V^T written by gemm0
  u16*   zB    = (u16*)w;   w += (size_t)M_ * HD_ * 2;

  prep_kernel<<<dim3(9216), 256, 0, stream>>>(x, Wq, Wk, Wv, Wo, xb, wqkvT, woT);
  gemm_bt_kernel<0><<<dim3(24, 64), 256, 0, stream>>>(xb, wqkvT, bq, bk, bv,
                                                      qB, kB, vT, nullptr);
  flash_kernel<<<dim3(1024), 256, 0, stream>>>(qB, kB, vT, zB);
  gemm_bt_kernel<1><<<dim3(8, 64), 256, 0, stream>>>(zB, woT, bo, nullptr, nullptr,
                                                     nullptr, nullptr, nullptr, out);
}

// Round 8
// 256.699 us; speedup vs baseline: 1.0389x; 1.0389x over previous
//
#include <hip/hip_runtime.h>
#include <hip/hip_bf16.h>

#define B_  4
#define S_  2048
#define E_  1024
#define H_  16
#define DH_ 64
#define M_  (B_*S_)    // 8192 rows
#define HD_ (H_*DH_)   // 1024

typedef unsigned short u16;
typedef __attribute__((ext_vector_type(8))) __bf16 bf16x8;
typedef __attribute__((ext_vector_type(4))) __bf16 bf16x4;
typedef __attribute__((ext_vector_type(4))) float  f32x4;

#if __has_builtin(__builtin_amdgcn_exp2f)
#define EXP2F __builtin_amdgcn_exp2f
#else
#define EXP2F __builtin_exp2f
#endif

// softmax scale folded into Q at QKV epilogue: 1/sqrt(64) * log2(e)
#define QSCALE 0.18033688011112042f

// ---- async global->LDS, 16B per lane ----
__device__ __forceinline__ void g2l16(const void* g, void* l) {
  __builtin_amdgcn_global_load_lds(
      (const __attribute__((address_space(1))) void*)g,
      (__attribute__((address_space(3))) void*)l, 16, 0, 0);
}

// RNE float -> bf16 bits (scalar path, used in prep only)
__device__ __forceinline__ u16 f2bf(float f) {
  union { float f; unsigned u; } v; v.f = f;
  unsigned r = v.u + 0x7FFFu + ((v.u >> 16) & 1u);
  return (u16)(r >> 16);
}

// ---------------- fused prep: cvt_x | pack_wqkv | pack_wo ----------------
__global__ __launch_bounds__(256) void prep_kernel(
    const float* __restrict__ x, const float* __restrict__ Wq,
    const float* __restrict__ Wk, const float* __restrict__ Wv,
    const float* __restrict__ Wo,
    u16* __restrict__ xb, u16* __restrict__ wqkvT, u16* __restrict__ woT) {
  __shared__ u16 tile[64][66];
  const int blk = blockIdx.x, tid = threadIdx.x;
  if (blk < 8192) {
    int i = blk * 256 + tid;
    float4 v = ((const float4*)x)[i];
    ushort4 o;
    o.x = f2bf(v.x); o.y = f2bf(v.y); o.z = f2bf(v.z); o.w = f2bf(v.w);
    ((ushort4*)xb)[i] = o;
  } else if (blk < 8960) {
    int b2 = blk - 8192;
    int p = b2 >> 8, h = (b2 >> 4) & 15, e0 = (b2 & 15) * 64;
    const float* src = (p == 0 ? Wq : (p == 1 ? Wk : Wv)) + h * (E_ * DH_);
#pragma unroll
    for (int r = 0; r < 16; ++r) {
      int idx = r * 256 + tid;
      int el = idx >> 6, d = idx & 63;
      tile[el][d] = f2bf(src[(e0 + el) * DH_ + d]);
    }
    __syncthreads();
    u16* dst = wqkvT + (p * HD_ + h * DH_) * E_;
#pragma unroll
    for (int r = 0; r < 16; ++r) {
      int idx = r * 256 + tid;
      int d = idx >> 6, el = idx & 63;
      dst[d * E_ + e0 + el] = tile[el][d];
    }
  } else {
    int b3 = blk - 8960;
    int c0 = (b3 >> 4) * 64, e0 = (b3 & 15) * 64;
#pragma unroll
    for (int r = 0; r < 16; ++r) {
      int idx = r * 256 + tid;
      int cl = idx >> 6, el = idx & 63;
      tile[cl][el] = f2bf(Wo[(c0 + cl) * E_ + e0 + el]);
    }
    __syncthreads();
#pragma unroll
    for (int r = 0; r < 16; ++r) {
      int idx = r * 256 + tid;
      int er = idx >> 6, cl = idx & 63;
      woT[(e0 + er) * HD_ + c0 + cl] = tile[cl][er];
    }
  }
}

// ---------------- GEMM (QKV): C[M][3072] = xb * wqkvT^T, 128x128 tiles ----
// QKV epilogue — bias, bf16, then LDS round-trip to emit 16B coalesced
// stores. Q/K in [m][cc] orientation; V written DIRECTLY as V^T [b,h,d,s].
// R3 NOTE: a 128x256 2-phase/setprio/counted-vmcnt variant (1 block/CU) was
// measured == this kernel; partial 8-phase grafts don't pay without the full
// template. Keep this 3-blocks/CU structure.
__global__ __launch_bounds__(256) void gemm_qkv_kernel(
    const u16* __restrict__ A, const u16* __restrict__ Bt,
    const float* __restrict__ b0, const float* __restrict__ b1,
    const float* __restrict__ b2,
    u16* __restrict__ oQ, u16* __restrict__ oK, u16* __restrict__ oV) {
  constexpr int K = 1024;
  __shared__ __align__(16) u16 smem[2 * 128 * 64];   // As | Bs; reused as C-tile
  u16* As = smem;
  u16* Bs = smem + 128 * 64;
  const int tid = threadIdx.x;
  const int lane = tid & 63, wv = tid >> 6;
  const int wm = (wv >> 1) * 64, wn = (wv & 1) * 64;
  const int q4 = lane >> 4, lm = lane & 15;
  const int tileM = blockIdx.y * 128, tileN = blockIdx.x * 128;

  const u16* gA[4]; const u16* gB[4]; u16* lA[4]; u16* lB[4];
#pragma unroll
  for (int rr = 0; rr < 4; ++rr) {
    int c = rr * 256 + tid;
    int r = c >> 3, sw = ((c & 7) ^ (r & 7)) * 8;
    gA[rr] = A + (size_t)(tileM + r) * K + sw;
    gB[rr] = Bt + (size_t)(tileN + r) * K + sw;
    lA[rr] = As + c * 8;
    lB[rr] = Bs + c * 8;
  }

  f32x4 acc[4][4] = {};

  int aoff[2][4], boff[2][4];
#pragma unroll
  for (int ks = 0; ks < 2; ++ks) {
#pragma unroll
    for (int i = 0; i < 4; ++i) {
      int ra = wm + i * 16 + lm;
      aoff[ks][i] = ra * 64 + (((ks * 4 + q4) ^ (ra & 7)) * 8);
      int rb = wn + i * 16 + lm;
      boff[ks][i] = rb * 64 + (((ks * 4 + q4) ^ (rb & 7)) * 8);
    }
  }

  for (int k0 = 0; k0 < K; k0 += 64) {
#pragma unroll
    for (int rr = 0; rr < 4; ++rr) {
      g2l16(gA[rr] + k0, lA[rr]);
      g2l16(gB[rr] + k0, lB[rr]);
    }
    __syncthreads();
#pragma unroll
    for (int ks = 0; ks < 2; ++ks) {
      bf16x8 af[4], bf[4];
#pragma unroll
      for (int i = 0; i < 4; ++i) af[i] = *(const bf16x8*)(As + aoff[ks][i]);
#pragma unroll
      for (int j = 0; j < 4; ++j) bf[j] = *(const bf16x8*)(Bs + boff[ks][j]);
#pragma unroll
      for (int i = 0; i < 4; ++i)
#pragma unroll
        for (int j = 0; j < 4; ++j)
          acc[i][j] = __builtin_amdgcn_mfma_f32_16x16x32_bf16(af[i], bf[j], acc[i][j], 0, 0, 0);
    }
    __syncthreads();
  }

  // ---- LDS round-trip epilogue (after final barrier, smem is free) ----
  u16* TT = smem;                        // 128 x 128 bf16, swizzled
  const int ccb = tileN & 1023;
  const int proj = tileN >> 10;          // uniform per block
  const float scl = (proj == 0 ? QSCALE : 1.0f);
  const float* bp = (proj == 0 ? b0 : (proj == 1 ? b1 : b2));
#pragma unroll
  for (int j = 0; j < 4; ++j) {
    int ncl = wn + j * 16 + lm;
    float bs = bp[ccb + ncl];
#pragma unroll
    for (int i = 0; i < 4; ++i) {
      int m0 = wm + i * 16 + q4 * 4;
      f32x4 vv;
#pragma unroll
      for (int r = 0; r < 4; ++r) vv[r] = (acc[i][j][r] + bs) * scl;
      bf16x4 ov = __builtin_convertvector(vv, bf16x4);
      if (proj < 2) {
        // orientation A: element (ml, ccl) at ml*128 + (ccl ^ 8*(ml&15))
        ushort4 us = *(ushort4*)&ov;
        TT[(m0 + 0) * 128 + (ncl ^ (8 * ((m0 + 0) & 15)))] = us.x;
        TT[(m0 + 1) * 128 + (ncl ^ (8 * ((m0 + 1) & 15)))] = us.y;
        TT[(m0 + 2) * 128 + (ncl ^ (8 * ((m0 + 2) & 15)))] = us.z;
        TT[(m0 + 3) * 128 + (ncl ^ (8 * ((m0 + 3) & 15)))] = us.w;
      } else {
        // orientation B: element (ccl, ml) at ccl*128 + (ml ^ 8*(ccl&15))
        *(bf16x4*)(TT + ncl * 128 + (m0 ^ (8 * (ncl & 15)))) = ov;  // b64
      }
    }
  }
  __syncthreads();
  if (proj < 2) {
    u16* optr = (proj == 0 ? oQ : oK);
#pragma unroll
    for (int rr = 0; rr < 8; ++rr) {
      int seg = rr * 256 + tid;
      int ml = seg >> 4, sc = (seg & 15) * 8;
      uint4 val = *(const uint4*)(TT + ml * 128 + (sc ^ (8 * (ml & 15))));
      *(uint4*)(optr + (size_t)(tileM + ml) * 1024 + ccb + sc) = val;
    }
  } else {
    const int bb = tileM >> 11, s0 = tileM & 2047;
#pragma unroll
    for (int rr = 0; rr < 8; ++rr) {
      int seg = rr * 256 + tid;
      int ccl = seg >> 4, sc = (seg & 15) * 8;
      int cc = ccb + ccl;
      int hh = cc >> 6, dd = cc & 63;
      uint4 val = *(const uint4*)(TT + ccl * 128 + (sc ^ (8 * (ccl & 15))));
      *(uint4*)(oV + ((size_t)(bb * 16 + hh) * 64 + dd) * 2048 + s0 + sc) = val;
    }
  }
}

// ---------------- GEMM (out-proj): C[M][1024] = zB * woT^T, 64x128 tiles ----
// R6: old 128x128 config had grid (8,64)=512 blocks = 2/CU — worst residency
// in the chain. New: BM=64 BN=128, grid 1024 = 4/CU, 4 waves of 32x64,
// LDS 24 KiB, same staging swizzle + MFMA pattern. XCD-bijective 1D swizzle:
// each XCD owns a contiguous M-stripe (A-stripe 2 MB + B 2 MB fits 4 MB L2).
__global__ __launch_bounds__(256) void gemm_o_kernel(
    const u16* __restrict__ A, const u16* __restrict__ Bt,
    const float* __restrict__ bo, float* __restrict__ oF) {
  constexpr int K = 1024;
  __shared__ __align__(16) u16 smem[(64 + 128) * 64];   // As(64x64) | Bs(128x64)
  u16* As = smem;
  u16* Bs = smem + 64 * 64;
  const int tid = threadIdx.x;
  const int lane = tid & 63, wv = tid >> 6;
  const int wm = (wv >> 1) * 32, wn = (wv & 1) * 64;
  const int q4 = lane >> 4, lm = lane & 15;

  // XCD-bijective swizzle over 1024 blocks (1024 % 8 == 0)
  const int bid = blockIdx.x;
  const int wg = (bid & 7) * 128 + (bid >> 3);
  const int tileN = (wg & 7) * 128, tileM = (wg >> 3) * 64;

  const u16* gA[2]; const u16* gB[4]; u16* lA[2]; u16* lB[4];
#pragma unroll
  for (int rr = 0; rr < 2; ++rr) {
    int c = rr * 256 + tid;
    int r = c >> 3, sw = ((c & 7) ^ (r & 7)) * 8;
    gA[rr] = A + (size_t)(tileM + r) * K + sw;
    lA[rr] = As + c * 8;
  }
#pragma unroll
  for (int rr = 0; rr < 4; ++rr) {
    int c = rr * 256 + tid;
    int r = c >> 3, sw = ((c & 7) ^ (r & 7)) * 8;
    gB[rr] = Bt + (size_t)(tileN + r) * K + sw;
    lB[rr] = Bs + c * 8;
  }

  f32x4 acc[2][4] = {};

  int aoff[2][2], boff[2][4];
#pragma unroll
  for (int ks = 0; ks < 2; ++ks) {
#pragma unroll
    for (int i = 0; i < 2; ++i) {
      int ra = wm + i * 16 + lm;
      aoff[ks][i] = ra * 64 + (((ks * 4 + q4) ^ (ra & 7)) * 8);
    }
#pragma unroll
    for (int j = 0; j < 4; ++j) {
      int rb = wn + j * 16 + lm;
      boff[ks][j] = rb * 64 + (((ks * 4 + q4) ^ (rb & 7)) * 8);
    }
  }

  for (int k0 = 0; k0 < K; k0 += 64) {
#pragma unroll
    for (int rr = 0; rr < 2; ++rr) g2l16(gA[rr] + k0, lA[rr]);
#pragma unroll
    for (int rr = 0; rr < 4; ++rr) g2l16(gB[rr] + k0, lB[rr]);
    __syncthreads();
#pragma unroll
    for (int ks = 0; ks < 2; ++ks) {
      bf16x8 af[2], bf[4];
#pragma unroll
      for (int i = 0; i < 2; ++i) af[i] = *(const bf16x8*)(As + aoff[ks][i]);
#pragma unroll
      for (int j = 0; j < 4; ++j) bf[j] = *(const bf16x8*)(Bs + boff[ks][j]);
#pragma unroll
      for (int i = 0; i < 2; ++i)
#pragma unroll
        for (int j = 0; j < 4; ++j)
          acc[i][j] = __builtin_amdgcn_mfma_f32_16x16x32_bf16(af[i], bf[j], acc[i][j], 0, 0, 0);
    }
    __syncthreads();
  }

#pragma unroll
  for (int j = 0; j < 4; ++j) {
    int n = tileN + wn + j * 16 + lm;
    float bs = bo[n];
#pragma unroll
    for (int i = 0; i < 2; ++i) {
      int m0 = tileM + wm + i * 16 + q4 * 4;
#pragma unroll
      for (int r = 0; r < 4; ++r) oF[(m0 + r) * HD_ + n] = acc[i][j][r] + bs;
    }
  }
}

// ---------------- flash attention — R4 proven config (REVERTED from R5) ----
// R4: 32 q-rows/wave, 128 q-rows/block, grid 1024 -> 4 blocks/CU, VGPR 56,
// occupancy 34%, 76.5 us. R5's QK-one-tile-ahead pipeline (triple-buffer K,
// dual S-state) REGRESSED to 92 us: MFMA-busy time unchanged, +15 us stall —
// source-level pipelining defeats the compiler scheduler (m131-m140 pattern).
// DO NOT re-pipeline this loop; gains require the full 8-phase co-design.
// KEY PERMUTATION: K rows staged at LDS slot s = kb*16+q4*4+r hold logical
// key kperm(s) = (kb&1)*32 + q4*8 + (kb>>1)*4 + r. The S^T-MFMA C-layout
// output IS the PV A-fragment layout per-lane; V keeps sequential key order.
// P never touches LDS.
// REGISTER RULE: keep launch_bounds (256,2); tighter -> spill storm.
__global__ __launch_bounds__(256, 2) void flash_kernel(
    const u16* __restrict__ Q, const u16* __restrict__ Kb,
    const u16* __restrict__ Vt, u16* __restrict__ Z) {
  __shared__ __align__(16) u16 Ks[2][64 * 64];   // [slot][d] swizzled, key-permuted
  __shared__ __align__(16) u16 Vs[2][64 * 64];   // [d][key] swizzled, sequential
  const int tid = threadIdx.x, lane = tid & 63, wv = tid >> 6;
  const int q4 = lane >> 4, lm = lane & 15;

  const int bid = blockIdx.x;
  const int bh = bid >> 4, qt = bid & 15;        // 16 consecutive blocks share (b,h) K/V
  const int b = bh >> 4, h = bh & 15;

  const u16* qbase = Q + ((size_t)(b * S_ + qt * 128)) * HD_ + h * DH_;
  const u16* kbase = Kb + (size_t)b * S_ * HD_ + h * DH_;
  const u16* vbase = Vt + ((size_t)(b * H_ + h)) * DH_ * S_;
  u16* zbase = Z + ((size_t)(b * S_ + qt * 128)) * HD_ + h * DH_;

  const int c0 = tid,       r0 = c0 >> 3, s0 = ((c0 & 7) ^ (r0 & 7)) * 8;
  const int c1 = tid + 256, r1 = c1 >> 3, s1 = ((c1 & 7) ^ (r1 & 7)) * 8;
  const int kr0 = ((r0 >> 4) & 1) * 32 + ((r0 >> 2) & 3) * 8 + (r0 >> 5) * 4 + (r0 & 3);
  const int kr1 = ((r1 >> 4) & 1) * 32 + ((r1 >> 2) & 3) * 8 + (r1 >> 5) * 4 + (r1 & 3);

  bf16x8 qf[2][2];
#pragma unroll
  for (int qs = 0; qs < 2; ++qs)
#pragma unroll
    for (int dc = 0; dc < 2; ++dc)
      qf[qs][dc] = *(const bf16x8*)(qbase + (wv * 32 + qs * 16 + lm) * HD_ + dc * 32 + q4 * 8);

  const bf16x8 ones = {(__bf16)1.f, (__bf16)1.f, (__bf16)1.f, (__bf16)1.f,
                       (__bf16)1.f, (__bf16)1.f, (__bf16)1.f, (__bf16)1.f};

  // fragment base offsets (d-chunk 0 / 1); kb/db contribute imm kb*1024/db*1024
  const int base0 = lm * 64 + ((q4 ^ (lm & 7)) * 8);
  const int base1 = lm * 64 + (((4 + q4) ^ (lm & 7)) * 8);

  f32x4 oacc[2][4] = {};
  f32x4 liacc[2] = {};

  {
    g2l16(kbase + kr0 * HD_ + s0, Ks[0] + c0 * 8);
    g2l16(kbase + kr1 * HD_ + s1, Ks[0] + c1 * 8);
    g2l16(vbase + r0 * S_ + s0, Vs[0] + c0 * 8);
    g2l16(vbase + r1 * S_ + s1, Vs[0] + c1 * 8);
  }

  for (int t = 0; t < 32; ++t) {
    const int pb = t & 1;
    __syncthreads();
    if (t < 31) {
      const u16* kt = kbase + (size_t)(t + 1) * 64 * HD_;
      const u16* vt = vbase + (t + 1) * 64;
      g2l16(kt + kr0 * HD_ + s0, Ks[1 - pb] + c0 * 8);
      g2l16(kt + kr1 * HD_ + s1, Ks[1 - pb] + c1 * 8);
      g2l16(vt + r0 * S_ + s0, Vs[1 - pb] + c0 * 8);
      g2l16(vt + r1 * S_ + s1, Vs[1 - pb] + c1 * 8);
    }
    const u16* Kp = Ks[pb];
    const u16* Vp = Vs[pb];

#pragma unroll
    for (int ck = 0; ck < 2; ++ck) {
      bf16x8 ka0 = *(const bf16x8*)(Kp + ck * 1024 + base0);
      bf16x8 ka1 = *(const bf16x8*)(Kp + ck * 1024 + base1);
      bf16x8 kb0 = *(const bf16x8*)(Kp + (ck + 2) * 1024 + base0);
      bf16x8 kb1 = *(const bf16x8*)(Kp + (ck + 2) * 1024 + base1);
      bf16x8 pf[2];
#pragma unroll
      for (int qs = 0; qs < 2; ++qs) {
        f32x4 sa = {}, sb = {};
        sa = __builtin_amdgcn_mfma_f32_16x16x32_bf16(ka0, qf[qs][0], sa, 0, 0, 0);
        sa = __builtin_amdgcn_mfma_f32_16x16x32_bf16(ka1, qf[qs][1], sa, 0, 0, 0);
        sb = __builtin_amdgcn_mfma_f32_16x16x32_bf16(kb0, qf[qs][0], sb, 0, 0, 0);
        sb = __builtin_amdgcn_mfma_f32_16x16x32_bf16(kb1, qf[qs][1], sb, 0, 0, 0);
        f32x4 pa, pb2;
#pragma unroll
        for (int r = 0; r < 4; ++r) { pa[r] = EXP2F(sa[r]); pb2[r] = EXP2F(sb[r]); }
        bf16x4 la = __builtin_convertvector(pa, bf16x4);
        bf16x4 lb = __builtin_convertvector(pb2, bf16x4);
        pf[qs] = __builtin_shufflevector(la, lb, 0, 1, 2, 3, 4, 5, 6, 7);
      }
      const int vsel = ck ? base1 : base0;
      __builtin_amdgcn_s_setprio(1);
#pragma unroll
      for (int qs = 0; qs < 2; ++qs)
        liacc[qs] = __builtin_amdgcn_mfma_f32_16x16x32_bf16(pf[qs], ones, liacc[qs], 0, 0, 0);
#pragma unroll
      for (int db = 0; db < 4; ++db) {
        bf16x8 vf = *(const bf16x8*)(Vp + db * 1024 + vsel);
#pragma unroll
        for (int qs = 0; qs < 2; ++qs)
          oacc[qs][db] = __builtin_amdgcn_mfma_f32_16x16x32_bf16(pf[qs], vf, oacc[qs][db], 0, 0, 0);
      }
      __builtin_amdgcn_s_setprio(0);
    }
  }

  // ---- normalize + store (wave owns its 32 q-rows; li is in-lane) ----
#pragma unroll
  for (int qs = 0; qs < 2; ++qs) {
    float rin[4];
#pragma unroll
    for (int r = 0; r < 4; ++r) rin[r] = 1.f / liacc[qs][r];
#pragma unroll
    for (int db = 0; db < 4; ++db) {
      f32x4 vv;
#pragma unroll
      for (int r = 0; r < 4; ++r) vv[r] = oacc[qs][db][r] * rin[r];
      bf16x4 ov = __builtin_convertvector(vv, bf16x4);
      ushort4 us = *(ushort4*)&ov;
      int m0 = wv * 32 + qs * 16 + q4 * 4;
      zbase[(m0 + 0) * HD_ + db * 16 + lm] = us.x;
      zbase[(m0 + 1) * HD_ + db * 16 + lm] = us.y;
      zbase[(m0 + 2) * HD_ + db * 16 + lm] = us.z;
      zbase[(m0 + 3) * HD_ + db * 16 + lm] = us.w;
    }
  }
}

// ---------------- host ----------------
extern "C" void kernel_launch(void* const* d_in, const int* in_sizes, int n_in,
                              void* d_out, int out_size, void* d_ws, size_t ws_size,
                              hipStream_t stream) {
  const float* x  = (const float*)d_in[0];
  const float* Wq = (const float*)d_in[1];
  const float* bq = (const float*)d_in[2];
  const float* Wk = (const float*)d_in[3];
  const float* bk = (const float*)d_in[4];
  const float* Wv = (const float*)d_in[5];
  const float* bv = (const float*)d_in[6];
  const float* Wo = (const float*)d_in[7];
  const float* bo = (const float*)d_in[8];
  float* out = (float*)d_out;

  char* w = (char*)d_ws;
  u16*   xb    = (u16*)w;   w += (size_t)M_ * E_ * 2;
  u16*   wqkvT = (u16*)w;   w += (size_t)3 * HD_ * E_ * 2;
  u16*   woT   = (u16*)w;   w += (size_t)E_ * HD_ * 2;
  u16*   qB    = (u16*)w;   w += (size_t)M_ * HD_ * 2;
  u16*   kB    = (u16*)w;   w += (size_t)M_ * HD_ * 2;
  u16*   vT    = (u16*)w;   w += (size_t)M_ * HD_ * 2;     // V^T written by gemm0
  u16*   zB    = (u16*)w;   w += (size_t)M_ * HD_ * 2;

  prep_kernel<<<dim3(9216), 256, 0, stream>>>(x, Wq, Wk, Wv, Wo, xb, wqkvT, woT);
  gemm_qkv_kernel<<<dim3(24, 64), 256, 0, stream>>>(xb, wqkvT, bq, bk, bv,
                                                    qB, kB, vT);
  flash_kernel<<<dim3(1024), 256, 0, stream>>>(qB, kB, vT, zB);
  gemm_o_kernel<<<dim3(1024), 256, 0, stream>>>(zB, woT, bo, out);
}